// Round 1
// baseline (153.472 us; speedup 1.0000x reference)
//
#include <hip/hip_runtime.h>
#include <math.h>

// Problem constants (from reference setup_inputs)
// p=2, j=32, k=32, m=32, l=8, n=32; B = 2*1024 = 2048 rows; K = k*n = 1024; Ncols = j*m = 1024.

__device__ __forceinline__ float fsign(float v) {
    return (v > 0.f) ? 1.f : ((v < 0.f) ? -1.f : 0.f);
}

// One block per (j,k). Computes Wtot[(k*32+n)*1024 + j*32+m] for all 32x32 (m,n).
// 256 threads: thread t handles m = t&31, n in { (t>>5) + 8*q : q=0..3 }.
__global__ __launch_bounds__(256) void precompute_wtot(
    const float* __restrict__ Y,   // (2,32,32,32,8)
    const float* __restrict__ Z,   // (2,32,32,8,32)
    const float* __restrict__ A,   // (2,32,32,4)
    float* __restrict__ Wtot)      // (1024,1024) row=k*32+n, col=j*32+m
{
    __shared__ float sgy[256];   // sign(Y) [m*8+l]
    __shared__ float sgz[256];   // sign(Z) [l*32+n]
    __shared__ float red[256];
    __shared__ float sYs, sZs;

    const int jk = blockIdx.x;        // 0..1023
    const int jj = jk >> 5;           // j
    const int kk = jk & 31;           // k
    const int t  = threadIdx.x;       // 0..255
    const int m  = t & 31;
    const int nb = t >> 5;            // 0..7

    float acc[4] = {0.f, 0.f, 0.f, 0.f};

    for (int p = 0; p < 2; ++p) {
        const int base = ((p * 32 + jj) * 32 + kk);
        const float yv = Y[(size_t)base * 256 + t];
        const float zv = Z[(size_t)base * 256 + t];
        sgy[t] = fsign(yv);
        sgz[t] = fsign(zv);

        // reduce |Y|
        red[t] = fabsf(yv);
        __syncthreads();
        for (int s2 = 128; s2 > 0; s2 >>= 1) {
            if (t < s2) red[t] += red[t + s2];
            __syncthreads();
        }
        if (t == 0) sYs = red[0] * (1.f / 256.f);
        __syncthreads();

        // reduce |Z|
        red[t] = fabsf(zv);
        __syncthreads();
        for (int s2 = 128; s2 > 0; s2 >>= 1) {
            if (t < s2) red[t] += red[t + s2];
            __syncthreads();
        }
        if (t == 0) sZs = red[0] * (1.f / 256.f);
        __syncthreads();

        const float sY = sYs;
        const float sZ = sZs;
        const float a0 = A[(size_t)base * 4 + 0];
        const float a1 = A[(size_t)base * 4 + 1];
        const float a2 = A[(size_t)base * 4 + 2];
        const float a3 = A[(size_t)base * 4 + 3];

        // Ysum[m] = sum_l sign(Y)[m,l]
        float ysum = 0.f;
        #pragma unroll
        for (int l = 0; l < 8; ++l) ysum += sgy[m * 8 + l];

        #pragma unroll
        for (int q = 0; q < 4; ++q) {
            const int n = nb + 8 * q;
            float zcol = 0.f, w = 0.f;
            #pragma unroll
            for (int l = 0; l < 8; ++l) {
                const float zs = sgz[l * 32 + n];
                zcol += zs;
                w += sgy[m * 8 + l] * zs;
            }
            acc[q] += a0 * sY * sZ * w + a1 * sY * ysum + a2 * sZ * zcol + a3;
        }
        __syncthreads();  // protect LDS before next p overwrites
    }

    #pragma unroll
    for (int q = 0; q < 4; ++q) {
        const int n = nb + 8 * q;
        Wtot[(size_t)(kk * 32 + n) * 1024 + jj * 32 + m] = acc[q];
    }
}

// out[row, col] = sum_k q8(x[row,k]) * Wtot[k, col] + bias[col]
// M=2048, K=1024, N=1024. 64x64 tile, BK=16, 4x4 per thread, 256 threads.
__global__ __launch_bounds__(256) void gemm_out(
    const float* __restrict__ x,        // (2048,1024)
    const float* __restrict__ Wtot,     // (1024,1024)
    const float* __restrict__ bias,     // (1024)
    const float* __restrict__ act_scale,// (1)
    float* __restrict__ out)            // (2048,1024)
{
    __shared__ float As[16][64];  // As[kk][row-in-tile]  (A transposed)
    __shared__ float Bs[16][64];  // Bs[kk][col-in-tile]

    const int t  = threadIdx.x;
    const int tx = t & 15;
    const int ty = t >> 4;
    const int rowBase = blockIdx.y * 64;
    const int colBase = blockIdx.x * 64;

    const float s = fmaxf(fabsf(act_scale[0]), 1e-8f);

    const int ar = t >> 2;        // 0..63 row within A tile
    const int ak = (t & 3) * 4;   // k offset within tile (0,4,8,12)
    const int br = t >> 4;        // 0..15 k row for B tile
    const int bc = (t & 15) * 4;  // col within tile

    float acc[4][4] = {};

    for (int k0 = 0; k0 < 1024; k0 += 16) {
        // A tile: quantized x
        const float4 xv = *(const float4*)(x + (size_t)(rowBase + ar) * 1024 + k0 + ak);
        float qx = fminf(fmaxf(rintf(xv.x / s), -127.f), 127.f) * s;
        float qy = fminf(fmaxf(rintf(xv.y / s), -127.f), 127.f) * s;
        float qz = fminf(fmaxf(rintf(xv.z / s), -127.f), 127.f) * s;
        float qw = fminf(fmaxf(rintf(xv.w / s), -127.f), 127.f) * s;
        As[ak + 0][ar] = qx;
        As[ak + 1][ar] = qy;
        As[ak + 2][ar] = qz;
        As[ak + 3][ar] = qw;

        // B tile
        const float4 wv = *(const float4*)(Wtot + (size_t)(k0 + br) * 1024 + colBase + bc);
        *(float4*)&Bs[br][bc] = wv;

        __syncthreads();

        #pragma unroll
        for (int kkk = 0; kkk < 16; ++kkk) {
            const float4 av = *(const float4*)&As[kkk][ty * 4];
            const float4 bv = *(const float4*)&Bs[kkk][tx * 4];
            const float a4[4] = {av.x, av.y, av.z, av.w};
            const float b4[4] = {bv.x, bv.y, bv.z, bv.w};
            #pragma unroll
            for (int i = 0; i < 4; ++i)
                #pragma unroll
                for (int jx = 0; jx < 4; ++jx)
                    acc[i][jx] = fmaf(a4[i], b4[jx], acc[i][jx]);
        }
        __syncthreads();
    }

    const float4 bv = *(const float4*)(bias + colBase + tx * 4);
    const float b4[4] = {bv.x, bv.y, bv.z, bv.w};
    #pragma unroll
    for (int i = 0; i < 4; ++i) {
        const int row = rowBase + ty * 4 + i;
        float4 o;
        o.x = acc[i][0] + b4[0];
        o.y = acc[i][1] + b4[1];
        o.z = acc[i][2] + b4[2];
        o.w = acc[i][3] + b4[3];
        *(float4*)(out + (size_t)row * 1024 + colBase + tx * 4) = o;
    }
}

extern "C" void kernel_launch(void* const* d_in, const int* in_sizes, int n_in,
                              void* d_out, int out_size, void* d_ws, size_t ws_size,
                              hipStream_t stream) {
    const float* x         = (const float*)d_in[0];  // (2,1024,1024)
    const float* Y_fp      = (const float*)d_in[1];  // (2,32,32,32,8)
    const float* Z_fp      = (const float*)d_in[2];  // (2,32,32,8,32)
    const float* A         = (const float*)d_in[3];  // (2,32,32,4)
    const float* bias      = (const float*)d_in[4];  // (1024)
    const float* act_scale = (const float*)d_in[5];  // (1)
    float* out = (float*)d_out;                      // (2048,1024)

    float* Wtot = (float*)d_ws;                      // 1024*1024*4 = 4 MB

    precompute_wtot<<<dim3(1024), dim3(256), 0, stream>>>(Y_fp, Z_fp, A, Wtot);
    gemm_out<<<dim3(16, 32), dim3(256), 0, stream>>>(x, Wtot, bias, act_scale, out);
}

// Round 2
// 93.033 us; speedup vs baseline: 1.6496x; 1.6496x over previous
//
#include <hip/hip_runtime.h>
#include <math.h>
#include <stdint.h>

// p=2, j=32, k=32, m=32, l=8, n=32; B=2048 rows; K=1024 (=k*n); N=1024 (=j*m).
//
// Algebra: out[b, jm] = s * sum_kn q[b,kn] * Wt[jm, kn] + bias[jm]
//   q = clip(rint(x/s), +-127)  (exact small integer -> exact in bf16)
//   Wt[(j,m),(k,n)] = sum_p a0*sY*sZ*W[m,n] + a1*sY*Ysum[m] + a2*sZ*Zcol[n] + a3
//   with W = sign(Y)*sign(Z) (8-term dot), Ysum/Zcol sign row/col sums.

typedef __attribute__((ext_vector_type(8))) short bf16x8;
typedef __attribute__((ext_vector_type(4))) float f32x4;
typedef __attribute__((ext_vector_type(4))) unsigned short us4;

__device__ __forceinline__ float fsign(float v) {
    return (v > 0.f) ? 1.f : ((v < 0.f) ? -1.f : 0.f);
}

// round-to-nearest-even float -> bf16 bits (finite inputs only)
__device__ __forceinline__ unsigned short f2bf(float f) {
    union { float f; uint32_t u; } c; c.f = f;
    uint32_t r = 0x7fffu + ((c.u >> 16) & 1u);
    return (unsigned short)((c.u + r) >> 16);
}

__device__ __forceinline__ void gl2lds16(const void* g, void* l) {
    __builtin_amdgcn_global_load_lds(
        (const __attribute__((address_space(1))) void*)g,
        (__attribute__((address_space(3))) void*)l, 16, 0, 0);
}

// ---------------------------------------------------------------------------
// Kernel 1: Wt[jm][kn] (bf16, N-major so GEMM B-frags read 8 contiguous k)
// One block per (j,k). Thread t: n = t&31, m in {t>>5 + 8q}.
__global__ __launch_bounds__(256) void precompute_wt(
    const float* __restrict__ Y,   // (2,32,32,32,8)
    const float* __restrict__ Z,   // (2,32,32,8,32)
    const float* __restrict__ A,   // (2,32,32,4)
    unsigned short* __restrict__ wt) // (1024 N, 1024 K) bf16 bits
{
    __shared__ float sgy[256];  // sign(Y)[m*8+l]
    __shared__ float sgz[256];  // sign(Z)[l*32+n]
    __shared__ float wred[8];   // per-wave partials (y,z interleaved)

    const int jk = blockIdx.x;
    const int jj = jk >> 5;
    const int kk = jk & 31;
    const int t  = threadIdx.x;
    const int n  = t & 31;
    const int mb = t >> 5;      // 0..7

    float acc[4] = {0.f, 0.f, 0.f, 0.f};

    for (int p = 0; p < 2; ++p) {
        const int base = ((p * 32 + jj) * 32 + kk);
        const float yv = Y[(size_t)base * 256 + t];
        const float zv = Z[(size_t)base * 256 + t];
        sgy[t] = fsign(yv);
        sgz[t] = fsign(zv);

        float ay = fabsf(yv), az = fabsf(zv);
        #pragma unroll
        for (int d = 1; d < 64; d <<= 1) {
            ay += __shfl_xor(ay, d, 64);
            az += __shfl_xor(az, d, 64);
        }
        if ((t & 63) == 0) {
            wred[(t >> 6) * 2 + 0] = ay;
            wred[(t >> 6) * 2 + 1] = az;
        }
        __syncthreads();  // sgy/sgz + wred visible

        const float sY = (wred[0] + wred[2] + wred[4] + wred[6]) * (1.f / 256.f);
        const float sZ = (wred[1] + wred[3] + wred[5] + wred[7]) * (1.f / 256.f);
        const float a0 = A[(size_t)base * 4 + 0];
        const float a1 = A[(size_t)base * 4 + 1];
        const float a2 = A[(size_t)base * 4 + 2];
        const float a3 = A[(size_t)base * 4 + 3];

        float zcol = 0.f;
        #pragma unroll
        for (int l = 0; l < 8; ++l) zcol += sgz[l * 32 + n];

        #pragma unroll
        for (int q = 0; q < 4; ++q) {
            const int m = mb + 8 * q;
            float ysum = 0.f, w = 0.f;
            #pragma unroll
            for (int l = 0; l < 8; ++l) {
                const float ys = sgy[m * 8 + l];
                ysum += ys;
                w += ys * sgz[l * 32 + n];
            }
            acc[q] += a0 * sY * sZ * w + a1 * sY * ysum + a2 * sZ * zcol + a3;
        }
        __syncthreads();  // protect LDS before next p overwrites
    }

    #pragma unroll
    for (int q = 0; q < 4; ++q) {
        const int m = mb + 8 * q;
        wt[(size_t)(jj * 32 + m) * 1024 + kk * 32 + n] = f2bf(acc[q]);
    }
}

// ---------------------------------------------------------------------------
// Kernel 2: q = clip(rint(x/s), +-127) stored as bf16 (exact integers)
__global__ __launch_bounds__(256) void quantize_x(
    const float* __restrict__ x, const float* __restrict__ act_scale,
    unsigned short* __restrict__ qx)
{
    const float s = fmaxf(fabsf(act_scale[0]), 1e-8f);
    const size_t i4 = (size_t)blockIdx.x * 256 + threadIdx.x;  // float4 index
    const float4 v = *(const float4*)(x + i4 * 4);
    us4 o;
    o.x = f2bf(fminf(fmaxf(rintf(v.x / s), -127.f), 127.f));
    o.y = f2bf(fminf(fmaxf(rintf(v.y / s), -127.f), 127.f));
    o.z = f2bf(fminf(fmaxf(rintf(v.z / s), -127.f), 127.f));
    o.w = f2bf(fminf(fmaxf(rintf(v.w / s), -127.f), 127.f));
    *(us4*)(qx + i4 * 4) = o;
}

// ---------------------------------------------------------------------------
// Kernel 3: out[2048,1024] = s * (Q[2048,1024(K)] x Wt[1024(N),1024(K)]^T) + bias
// Tile 64(M) x 128(N), BK=32, 4 waves as 2x2, each wave 32x64 (2x4 of 16x16).
__global__ __launch_bounds__(256) void gemm_mfma(
    const unsigned short* __restrict__ qx,   // (2048,1024) bf16 bits
    const unsigned short* __restrict__ wt,   // (1024 N,1024 K) bf16 bits
    const float* __restrict__ bias,          // (1024)
    const float* __restrict__ act_scale,     // (1)
    float* __restrict__ out)                 // (2048,1024)
{
    __shared__ __align__(16) short lds[64 * 32 + 128 * 32];  // A 4KB + B 8KB
    short* As = lds;             // [row][k] 64x32
    short* Bs = lds + 64 * 32;   // [n][k]  128x32

    const int tid  = threadIdx.x;
    const int lane = tid & 63;
    const int wave = tid >> 6;
    const int wm = wave >> 1;    // 0..1
    const int wn = wave & 1;     // 0..1
    const int rowBase = blockIdx.y * 64;
    const int colBase = blockIdx.x * 128;

    const float s = fmaxf(fabsf(act_scale[0]), 1e-8f);

    f32x4 acc[2][4];
    #pragma unroll
    for (int i = 0; i < 2; ++i)
        #pragma unroll
        for (int jx = 0; jx < 4; ++jx)
            acc[i][jx] = (f32x4)0.f;

    // staging: 16B chunk per lane. A tile: 256 chunks (1 issue). B: 512 (2).
    const unsigned short* agp =
        qx + (size_t)(rowBase + (tid >> 2)) * 1024 + (tid & 3) * 8;
    const unsigned short* bgp0 =
        wt + (size_t)(colBase + (tid >> 2)) * 1024 + (tid & 3) * 8;
    const unsigned short* bgp1 = bgp0 + (size_t)64 * 1024;

    char* const ldsc = (char*)lds;
    void* aw  = ldsc + wave * 1024;                 // A dst (wave-uniform)
    void* bw0 = ldsc + 4096 + wave * 1024;          // B issue-0 dst
    void* bw1 = ldsc + 4096 + 4096 + wave * 1024;   // B issue-1 dst

    const int q4  = lane >> 4;   // quad
    const int l16 = lane & 15;

    for (int k0 = 0; k0 < 1024; k0 += 32) {
        gl2lds16(agp  + k0, aw);
        gl2lds16(bgp0 + k0, bw0);
        gl2lds16(bgp1 + k0, bw1);
        __syncthreads();  // drains vmcnt + barrier

        bf16x8 af[2], bfr[4];
        #pragma unroll
        for (int im = 0; im < 2; ++im)
            af[im] = *(const bf16x8*)&As[(wm * 32 + im * 16 + l16) * 32 + q4 * 8];
        #pragma unroll
        for (int in = 0; in < 4; ++in)
            bfr[in] = *(const bf16x8*)&Bs[(wn * 64 + in * 16 + l16) * 32 + q4 * 8];

        #pragma unroll
        for (int im = 0; im < 2; ++im)
            #pragma unroll
            for (int in = 0; in < 4; ++in)
                acc[im][in] = __builtin_amdgcn_mfma_f32_16x16x32_bf16(
                    af[im], bfr[in], acc[im][in], 0, 0, 0);

        __syncthreads();  // before next overwrite
    }

    // epilogue: C/D layout col = lane&15, row = quad*4 + reg
    #pragma unroll
    for (int im = 0; im < 2; ++im) {
        #pragma unroll
        for (int in = 0; in < 4; ++in) {
            const int col = colBase + wn * 64 + in * 16 + l16;
            const float b = bias[col];
            #pragma unroll
            for (int r = 0; r < 4; ++r) {
                const int row = rowBase + wm * 32 + im * 16 + q4 * 4 + r;
                out[(size_t)row * 1024 + col] = s * acc[im][in][r] + b;
            }
        }
    }
}

extern "C" void kernel_launch(void* const* d_in, const int* in_sizes, int n_in,
                              void* d_out, int out_size, void* d_ws, size_t ws_size,
                              hipStream_t stream) {
    const float* x         = (const float*)d_in[0];  // (2,1024,1024)
    const float* Y_fp      = (const float*)d_in[1];  // (2,32,32,32,8)
    const float* Z_fp      = (const float*)d_in[2];  // (2,32,32,8,32)
    const float* A         = (const float*)d_in[3];  // (2,32,32,4)
    const float* bias      = (const float*)d_in[4];  // (1024)
    const float* act_scale = (const float*)d_in[5];  // (1)
    float* out = (float*)d_out;                      // (2048,1024)

    unsigned short* wt = (unsigned short*)d_ws;                    // 2 MB
    unsigned short* qx = (unsigned short*)((char*)d_ws + 2 * 1024 * 1024); // 4 MB

    precompute_wt<<<dim3(1024), dim3(256), 0, stream>>>(Y_fp, Z_fp, A, wt);
    quantize_x<<<dim3(2048), dim3(256), 0, stream>>>(x, act_scale, qx);
    gemm_mfma<<<dim3(8, 32), dim3(256), 0, stream>>>(qx, wt, bias, act_scale, out);
}

// Round 3
// 87.491 us; speedup vs baseline: 1.7541x; 1.0633x over previous
//
#include <hip/hip_runtime.h>
#include <math.h>
#include <stdint.h>

// p=2, j=32, k=32, m=32, l=8, n=32; B=2048 rows; K=1024 (=k*n); N=1024 (=j*m).
//
// Algebra: out[b, jm] = s * sum_kn q[b,kn] * Wt[jm, kn] + bias[jm]
//   q = clip(rint(x/s), +-127)  (exact small integer -> exact in bf16)
//   Wt[(j,m),(k,n)] = sum_p a0*sY*sZ*W[m,n] + a1*sY*Ysum[m] + a2*sZ*Zcol[n] + a3

typedef __attribute__((ext_vector_type(8))) short bf16x8;
typedef __attribute__((ext_vector_type(4))) float f32x4;
typedef __attribute__((ext_vector_type(4))) unsigned short us4;

__device__ __forceinline__ float fsign(float v) {
    return (v > 0.f) ? 1.f : ((v < 0.f) ? -1.f : 0.f);
}

__device__ __forceinline__ unsigned short f2bf(float f) {
    union { float f; uint32_t u; } c; c.f = f;
    uint32_t r = 0x7fffu + ((c.u >> 16) & 1u);
    return (unsigned short)((c.u + r) >> 16);
}

__device__ __forceinline__ void gl2lds16(const void* g, void* l) {
    __builtin_amdgcn_global_load_lds(
        (const __attribute__((address_space(1))) void*)g,
        (__attribute__((address_space(3))) void*)l, 16, 0, 0);
}

// ---------------------------------------------------------------------------
// Fused: blocks [0,1024) compute one (j,k) tile of Wt (bf16, N-major);
//        blocks [1024,1536) quantize x -> qx (bf16 integers).
__global__ __launch_bounds__(256) void fused_pre(
    const float* __restrict__ Y,     // (2,32,32,32,8)
    const float* __restrict__ Z,     // (2,32,32,8,32)
    const float* __restrict__ A,     // (2,32,32,4)
    const float* __restrict__ x,     // (2048,1024)
    const float* __restrict__ act_scale,
    unsigned short* __restrict__ wt, // (1024 N, 1024 K) bf16 bits
    unsigned short* __restrict__ qx) // (2048,1024) bf16 bits
{
    const int t = threadIdx.x;

    if (blockIdx.x >= 1024) {
        // ---- quantize branch: 512 blocks x 256 threads x 4 float4 ----
        const float s = fmaxf(fabsf(act_scale[0]), 1e-8f);
        const int b2 = blockIdx.x - 1024;
        #pragma unroll
        for (int it = 0; it < 4; ++it) {
            const size_t i4 = (size_t)b2 * 256 + t + (size_t)it * 131072;
            const float4 v = *(const float4*)(x + i4 * 4);
            us4 o;
            o.x = f2bf(fminf(fmaxf(rintf(v.x / s), -127.f), 127.f));
            o.y = f2bf(fminf(fmaxf(rintf(v.y / s), -127.f), 127.f));
            o.z = f2bf(fminf(fmaxf(rintf(v.z / s), -127.f), 127.f));
            o.w = f2bf(fminf(fmaxf(rintf(v.w / s), -127.f), 127.f));
            *(us4*)(qx + i4 * 4) = o;
        }
        return;
    }

    // ---- Wt branch ----
    __shared__ float sgy[256];  // sign(Y)[m*8+l]
    __shared__ float sgz[256];  // sign(Z)[l*32+n]
    __shared__ float wred[8];

    const int jk = blockIdx.x;
    const int jj = jk >> 5;
    const int kk = jk & 31;
    const int n  = t & 31;
    const int mb = t >> 5;      // 0..7

    float acc[4] = {0.f, 0.f, 0.f, 0.f};

    for (int p = 0; p < 2; ++p) {
        const int base = ((p * 32 + jj) * 32 + kk);
        const float yv = Y[(size_t)base * 256 + t];
        const float zv = Z[(size_t)base * 256 + t];
        sgy[t] = fsign(yv);
        sgz[t] = fsign(zv);

        float ay = fabsf(yv), az = fabsf(zv);
        #pragma unroll
        for (int d = 1; d < 64; d <<= 1) {
            ay += __shfl_xor(ay, d, 64);
            az += __shfl_xor(az, d, 64);
        }
        if ((t & 63) == 0) {
            wred[(t >> 6) * 2 + 0] = ay;
            wred[(t >> 6) * 2 + 1] = az;
        }
        __syncthreads();

        const float sY = (wred[0] + wred[2] + wred[4] + wred[6]) * (1.f / 256.f);
        const float sZ = (wred[1] + wred[3] + wred[5] + wred[7]) * (1.f / 256.f);
        const float a0 = A[(size_t)base * 4 + 0];
        const float a1 = A[(size_t)base * 4 + 1];
        const float a2 = A[(size_t)base * 4 + 2];
        const float a3 = A[(size_t)base * 4 + 3];

        float zcol = 0.f;
        #pragma unroll
        for (int l = 0; l < 8; ++l) zcol += sgz[l * 32 + n];

        #pragma unroll
        for (int q = 0; q < 4; ++q) {
            const int m = mb + 8 * q;
            float ysum = 0.f, w = 0.f;
            #pragma unroll
            for (int l = 0; l < 8; ++l) {
                const float ys = sgy[m * 8 + l];
                ysum += ys;
                w += ys * sgz[l * 32 + n];
            }
            acc[q] += a0 * sY * sZ * w + a1 * sY * ysum + a2 * sZ * zcol + a3;
        }
        __syncthreads();
    }

    #pragma unroll
    for (int q = 0; q < 4; ++q) {
        const int m = mb + 8 * q;
        wt[(size_t)(jj * 32 + m) * 1024 + kk * 32 + n] = f2bf(acc[q]);
    }
}

// ---------------------------------------------------------------------------
// GEMM: out[2048,1024] = s * (Q[2048,K] x Wt[1024 N,K]^T) + bias
// 64(M) x 128(N) tile, BK=32, 4 waves 2x2, double-buffered LDS with
// prefetch-after-barrier (loads in flight during MFMA burst).
__global__ __launch_bounds__(256) void gemm_mfma(
    const unsigned short* __restrict__ qx,   // (2048,1024) bf16 bits
    const unsigned short* __restrict__ wt,   // (1024,1024) bf16 bits
    const float* __restrict__ bias,          // (1024)
    const float* __restrict__ act_scale,     // (1)
    float* __restrict__ out)                 // (2048,1024)
{
    // one buffer = A 64x32 (4KB) + B 128x32 (8KB) = 6144 shorts
    __shared__ __align__(16) short lds[2 * 6144];

    const int tid  = threadIdx.x;
    const int lane = tid & 63;
    const int wave = tid >> 6;
    const int wm = wave >> 1;
    const int wn = wave & 1;
    const int rowBase = blockIdx.y * 64;
    const int colBase = blockIdx.x * 128;

    const float s = fmaxf(fabsf(act_scale[0]), 1e-8f);

    f32x4 acc[2][4];
    #pragma unroll
    for (int i = 0; i < 2; ++i)
        #pragma unroll
        for (int jx = 0; jx < 4; ++jx)
            acc[i][jx] = (f32x4)0.f;

    // staging ptrs: lane chunk = 16B; A tile 1 issue, B tile 2 issues
    const unsigned short* agp =
        qx + (size_t)(rowBase + (tid >> 2)) * 1024 + (tid & 3) * 8;
    const unsigned short* bgp0 =
        wt + (size_t)(colBase + (tid >> 2)) * 1024 + (tid & 3) * 8;
    const unsigned short* bgp1 = bgp0 + (size_t)64 * 1024;

    char* const ldsc = (char*)lds;
    const int q4  = lane >> 4;
    const int l16 = lane & 15;

    // prologue: stage k=0 into buffer 0
    {
        char* b = ldsc;
        gl2lds16(agp,  b + wave * 1024);
        gl2lds16(bgp0, b + 4096 + wave * 1024);
        gl2lds16(bgp1, b + 8192 + wave * 1024);
    }

    for (int kt = 0; kt < 32; ++kt) {
        __syncthreads();  // vmcnt(0)+lgkmcnt(0) drain: current buffer ready
        const int cur = kt & 1;

        if (kt + 1 < 32) {
            const int k1 = (kt + 1) * 32;
            char* b = ldsc + (cur ^ 1) * 12288;
            gl2lds16(agp  + k1, b + wave * 1024);
            gl2lds16(bgp0 + k1, b + 4096 + wave * 1024);
            gl2lds16(bgp1 + k1, b + 8192 + wave * 1024);
        }

        const short* As = lds + cur * 6144;          // [row][k] 64x32
        const short* Bs = As + 2048;                 // [n][k]  128x32

        bf16x8 af[2], bfr[4];
        #pragma unroll
        for (int im = 0; im < 2; ++im)
            af[im] = *(const bf16x8*)&As[(wm * 32 + im * 16 + l16) * 32 + q4 * 8];
        #pragma unroll
        for (int in = 0; in < 4; ++in)
            bfr[in] = *(const bf16x8*)&Bs[(wn * 64 + in * 16 + l16) * 32 + q4 * 8];

        #pragma unroll
        for (int im = 0; im < 2; ++im)
            #pragma unroll
            for (int in = 0; in < 4; ++in)
                acc[im][in] = __builtin_amdgcn_mfma_f32_16x16x32_bf16(
                    af[im], bfr[in], acc[im][in], 0, 0, 0);
    }

    // epilogue: C/D layout col = lane&15, row = quad*4 + reg
    #pragma unroll
    for (int im = 0; im < 2; ++im) {
        #pragma unroll
        for (int in = 0; in < 4; ++in) {
            const int col = colBase + wn * 64 + in * 16 + l16;
            const float b = bias[col];
            #pragma unroll
            for (int r = 0; r < 4; ++r) {
                const int row = rowBase + wm * 32 + im * 16 + q4 * 4 + r;
                out[(size_t)row * 1024 + col] = s * acc[im][in][r] + b;
            }
        }
    }
}

extern "C" void kernel_launch(void* const* d_in, const int* in_sizes, int n_in,
                              void* d_out, int out_size, void* d_ws, size_t ws_size,
                              hipStream_t stream) {
    const float* x         = (const float*)d_in[0];  // (2,1024,1024)
    const float* Y_fp      = (const float*)d_in[1];  // (2,32,32,32,8)
    const float* Z_fp      = (const float*)d_in[2];  // (2,32,32,8,32)
    const float* A         = (const float*)d_in[3];  // (2,32,32,4)
    const float* bias      = (const float*)d_in[4];  // (1024)
    const float* act_scale = (const float*)d_in[5];  // (1)
    float* out = (float*)d_out;                      // (2048,1024)

    unsigned short* wt = (unsigned short*)d_ws;                            // 2 MB
    unsigned short* qx = (unsigned short*)((char*)d_ws + 2 * 1024 * 1024); // 4 MB

    fused_pre<<<dim3(1536), dim3(256), 0, stream>>>(Y_fp, Z_fp, A, x, act_scale, wt, qx);
    gemm_mfma<<<dim3(8, 32), dim3(256), 0, stream>>>(qx, wt, bias, act_scale, out);
}

// Round 4
// 86.951 us; speedup vs baseline: 1.7650x; 1.0062x over previous
//
#include <hip/hip_runtime.h>
#include <math.h>
#include <stdint.h>

// p=2, j=32, k=32, m=32, l=8, n=32; B=2048 rows; K=1024 (=k*n); N=1024 (=j*m).
//
// out[b, jm] = s * sum_kn q[b,kn] * Wt[jm, kn] + bias[jm]
//   q = clip(rint(x/s), +-127)   (small integer -> exact in bf16)
//   Wt[(j,m),(k,n)] = sum_p a0*sY*sZ*W[m,n] + a1*sY*Ysum[m] + a2*sZ*Zcol[n] + a3

typedef __attribute__((ext_vector_type(8))) short bf16x8;
typedef __attribute__((ext_vector_type(4))) float f32x4;
typedef __attribute__((ext_vector_type(4))) unsigned short us4;

__device__ __forceinline__ float fsign(float v) {
    return (v > 0.f) ? 1.f : ((v < 0.f) ? -1.f : 0.f);
}

__device__ __forceinline__ unsigned short f2bf(float f) {
    union { float f; uint32_t u; } c; c.f = f;
    uint32_t r = 0x7fffu + ((c.u >> 16) & 1u);
    return (unsigned short)((c.u + r) >> 16);
}

__device__ __forceinline__ void gl2lds16(const void* g, void* l) {
    __builtin_amdgcn_global_load_lds(
        (const __attribute__((address_space(1))) void*)g,
        (__attribute__((address_space(3))) void*)l, 16, 0, 0);
}

// ---------------------------------------------------------------------------
// Fused: blocks [0,1024) -> one (j,k) tile of Wt (bf16, N-major);
//        blocks [1024,1536) -> quantize x -> qx.
__global__ __launch_bounds__(256) void fused_pre(
    const float* __restrict__ Y,     // (2,32,32,32,8)
    const float* __restrict__ Z,     // (2,32,32,8,32)
    const float* __restrict__ A,     // (2,32,32,4)
    const float* __restrict__ x,     // (2048,1024)
    const float* __restrict__ act_scale,
    unsigned short* __restrict__ wt, // (1024 N, 1024 K) bf16 bits
    unsigned short* __restrict__ qx) // (2048,1024) bf16 bits
{
    const int t = threadIdx.x;

    if (blockIdx.x >= 1024) {
        const float s = fmaxf(fabsf(act_scale[0]), 1e-8f);
        const int b2 = blockIdx.x - 1024;
        #pragma unroll
        for (int it = 0; it < 4; ++it) {
            const size_t i4 = (size_t)b2 * 256 + t + (size_t)it * 131072;
            const float4 v = *(const float4*)(x + i4 * 4);
            us4 o;
            o.x = f2bf(fminf(fmaxf(rintf(v.x / s), -127.f), 127.f));
            o.y = f2bf(fminf(fmaxf(rintf(v.y / s), -127.f), 127.f));
            o.z = f2bf(fminf(fmaxf(rintf(v.z / s), -127.f), 127.f));
            o.w = f2bf(fminf(fmaxf(rintf(v.w / s), -127.f), 127.f));
            *(us4*)(qx + i4 * 4) = o;
        }
        return;
    }

    __shared__ float sgy[2][256];  // sign(Y)[p][m*8+l]
    __shared__ float sgz[2][256];  // sign(Z)[p][l*32+n]
    __shared__ float wred[16];     // per-wave partials: w*4 + {ay0,az0,ay1,az1}

    const int jk = blockIdx.x;
    const int jj = jk >> 5;
    const int kk = jk & 31;
    const int n  = t & 31;
    const int mb = t >> 5;

    const int base0 = jj * 32 + kk;
    const int base1 = 1024 + base0;

    // all 4 big loads in flight at once
    const float yv0 = Y[(size_t)base0 * 256 + t];
    const float yv1 = Y[(size_t)base1 * 256 + t];
    const float zv0 = Z[(size_t)base0 * 256 + t];
    const float zv1 = Z[(size_t)base1 * 256 + t];
    const float a00 = A[(size_t)base0 * 4 + 0], a01 = A[(size_t)base0 * 4 + 1];
    const float a02 = A[(size_t)base0 * 4 + 2], a03 = A[(size_t)base0 * 4 + 3];
    const float a10 = A[(size_t)base1 * 4 + 0], a11 = A[(size_t)base1 * 4 + 1];
    const float a12 = A[(size_t)base1 * 4 + 2], a13 = A[(size_t)base1 * 4 + 3];

    sgy[0][t] = fsign(yv0);
    sgy[1][t] = fsign(yv1);
    sgz[0][t] = fsign(zv0);
    sgz[1][t] = fsign(zv1);

    float ay0 = fabsf(yv0), az0 = fabsf(zv0);
    float ay1 = fabsf(yv1), az1 = fabsf(zv1);
    #pragma unroll
    for (int d = 1; d < 64; d <<= 1) {
        ay0 += __shfl_xor(ay0, d, 64);
        az0 += __shfl_xor(az0, d, 64);
        ay1 += __shfl_xor(ay1, d, 64);
        az1 += __shfl_xor(az1, d, 64);
    }
    if ((t & 63) == 0) {
        const int w = t >> 6;
        wred[w * 4 + 0] = ay0;
        wred[w * 4 + 1] = az0;
        wred[w * 4 + 2] = ay1;
        wred[w * 4 + 3] = az1;
    }
    __syncthreads();

    const float sY0 = (wred[0] + wred[4] + wred[8]  + wred[12]) * (1.f / 256.f);
    const float sZ0 = (wred[1] + wred[5] + wred[9]  + wred[13]) * (1.f / 256.f);
    const float sY1 = (wred[2] + wred[6] + wred[10] + wred[14]) * (1.f / 256.f);
    const float sZ1 = (wred[3] + wred[7] + wred[11] + wred[15]) * (1.f / 256.f);

    float zcol0 = 0.f, zcol1 = 0.f;
    #pragma unroll
    for (int l = 0; l < 8; ++l) {
        zcol0 += sgz[0][l * 32 + n];
        zcol1 += sgz[1][l * 32 + n];
    }

    #pragma unroll
    for (int q = 0; q < 4; ++q) {
        const int m = mb + 8 * q;
        float ysum0 = 0.f, w0 = 0.f, ysum1 = 0.f, w1 = 0.f;
        #pragma unroll
        for (int l = 0; l < 8; ++l) {
            const float ys0 = sgy[0][m * 8 + l];
            const float ys1 = sgy[1][m * 8 + l];
            ysum0 += ys0;
            ysum1 += ys1;
            w0 += ys0 * sgz[0][l * 32 + n];
            w1 += ys1 * sgz[1][l * 32 + n];
        }
        const float acc =
            a00 * sY0 * sZ0 * w0 + a01 * sY0 * ysum0 + a02 * sZ0 * zcol0 + a03 +
            a10 * sY1 * sZ1 * w1 + a11 * sY1 * ysum1 + a12 * sZ1 * zcol1 + a13;
        wt[(size_t)(jj * 32 + m) * 1024 + kk * 32 + n] = f2bf(acc);
    }
}

// ---------------------------------------------------------------------------
// GEMM: out[2048,1024] = s * (Q[2048,K] x Wt[1024 N,K]^T) + bias
// 64(M) x 128(N) tile, BK=32, 4 waves 2x2. Triple-buffered LDS, manual
// s_barrier + fine-grained vmcnt (never vmcnt(0) in steady state):
//   iter kt: wait vmcnt(6) [tile kt staged] -> barrier -> ds_read frags
//            -> lgkmcnt(0) -> barrier -> issue tile kt+3 -> MFMAs
__global__ __launch_bounds__(256) void gemm_mfma(
    const unsigned short* __restrict__ qx,   // (2048,1024) bf16 bits
    const unsigned short* __restrict__ wt,   // (1024,1024) bf16 bits
    const float* __restrict__ bias,          // (1024)
    const float* __restrict__ act_scale,     // (1)
    float* __restrict__ out)                 // (2048,1024)
{
    // one buffer = A 64x32 (4KB) + B 128x32 (8KB) = 12KB; 3 buffers = 36KB
    __shared__ __align__(16) short lds[3 * 6144];

    const int tid  = threadIdx.x;
    const int lane = tid & 63;
    const int wave = tid >> 6;
    const int wm = wave >> 1;
    const int wn = wave & 1;
    const int rowBase = blockIdx.y * 64;
    const int colBase = blockIdx.x * 128;

    const float s = fmaxf(fabsf(act_scale[0]), 1e-8f);

    f32x4 acc[2][4];
    #pragma unroll
    for (int i = 0; i < 2; ++i)
        #pragma unroll
        for (int jx = 0; jx < 4; ++jx)
            acc[i][jx] = (f32x4)0.f;

    const unsigned short* agp =
        qx + (size_t)(rowBase + (tid >> 2)) * 1024 + (tid & 3) * 8;
    const unsigned short* bgp0 =
        wt + (size_t)(colBase + (tid >> 2)) * 1024 + (tid & 3) * 8;
    const unsigned short* bgp1 = bgp0 + (size_t)64 * 1024;

    char* const ldsc = (char*)lds;
    const int q4  = lane >> 4;
    const int l16 = lane & 15;
    const int woff = wave * 1024;

    // prologue: stage tiles 0,1,2 (9 outstanding vmem-lds loads per thread)
    #pragma unroll
    for (int tpre = 0; tpre < 3; ++tpre) {
        char* b = ldsc + tpre * 12288;
        gl2lds16(agp  + tpre * 32, b + woff);
        gl2lds16(bgp0 + tpre * 32, b + 4096 + woff);
        gl2lds16(bgp1 + tpre * 32, b + 8192 + woff);
    }

    #pragma unroll 1
    for (int kt = 0; kt < 32; ++kt) {
        // wait until tile kt's 3 loads retired (vmcnt retires in order)
        if (kt < 30)       asm volatile("s_waitcnt vmcnt(6)" ::: "memory");
        else if (kt == 30) asm volatile("s_waitcnt vmcnt(3)" ::: "memory");
        else               asm volatile("s_waitcnt vmcnt(0)" ::: "memory");
        __builtin_amdgcn_s_barrier();   // all waves' tile-kt data visible

        const int cur = kt % 3;
        const short* As = lds + cur * 6144;   // [row][k] 64x32
        const short* Bs = As + 2048;          // [n][k]  128x32

        bf16x8 af[2], bfr[4];
        #pragma unroll
        for (int im = 0; im < 2; ++im)
            af[im] = *(const bf16x8*)&As[(wm * 32 + im * 16 + l16) * 32 + q4 * 8];
        #pragma unroll
        for (int in = 0; in < 4; ++in)
            bfr[in] = *(const bf16x8*)&Bs[(wn * 64 + in * 16 + l16) * 32 + q4 * 8];

        // frags now requested; ensure they are in regs before buffer reuse
        asm volatile("s_waitcnt lgkmcnt(0)" ::: "memory");
        __builtin_amdgcn_s_barrier();   // all waves done reading buf cur

        if (kt + 3 < 32) {              // overwrite buf cur with tile kt+3
            const int k3 = (kt + 3) * 32;
            char* b = ldsc + cur * 12288;
            gl2lds16(agp  + k3, b + woff);
            gl2lds16(bgp0 + k3, b + 4096 + woff);
            gl2lds16(bgp1 + k3, b + 8192 + woff);
        }

        #pragma unroll
        for (int im = 0; im < 2; ++im)
            #pragma unroll
            for (int in = 0; in < 4; ++in)
                acc[im][in] = __builtin_amdgcn_mfma_f32_16x16x32_bf16(
                    af[im], bfr[in], acc[im][in], 0, 0, 0);
    }

    // epilogue: C/D layout col = lane&15, row = quad*4 + reg
    #pragma unroll
    for (int im = 0; im < 2; ++im) {
        #pragma unroll
        for (int in = 0; in < 4; ++in) {
            const int col = colBase + wn * 64 + in * 16 + l16;
            const float b = bias[col];
            #pragma unroll
            for (int r = 0; r < 4; ++r) {
                const int row = rowBase + wm * 32 + im * 16 + q4 * 4 + r;
                out[(size_t)row * 1024 + col] = s * acc[im][in][r] + b;
            }
        }
    }
}

extern "C" void kernel_launch(void* const* d_in, const int* in_sizes, int n_in,
                              void* d_out, int out_size, void* d_ws, size_t ws_size,
                              hipStream_t stream) {
    const float* x         = (const float*)d_in[0];  // (2,1024,1024)
    const float* Y_fp      = (const float*)d_in[1];  // (2,32,32,32,8)
    const float* Z_fp      = (const float*)d_in[2];  // (2,32,32,8,32)
    const float* A         = (const float*)d_in[3];  // (2,32,32,4)
    const float* bias      = (const float*)d_in[4];  // (1024)
    const float* act_scale = (const float*)d_in[5];  // (1)
    float* out = (float*)d_out;                      // (2048,1024)

    unsigned short* wt = (unsigned short*)d_ws;                            // 2 MB
    unsigned short* qx = (unsigned short*)((char*)d_ws + 2 * 1024 * 1024); // 4 MB

    fused_pre<<<dim3(1536), dim3(256), 0, stream>>>(Y_fp, Z_fp, A, x, act_scale, wt, qx);
    gemm_mfma<<<dim3(8, 32), dim3(256), 0, stream>>>(qx, wt, bias, act_scale, out);
}

// Round 5
// 82.690 us; speedup vs baseline: 1.8560x; 1.0515x over previous
//
#include <hip/hip_runtime.h>
#include <math.h>
#include <stdint.h>

// p=2, j=32, k=32, m=32, l=8, n=32; B=2048 rows; K=1024 (=k*n); N=1024 (=j*m).
//
// out[b, jm] = s * sum_kn q[b,kn] * Wt[jm, kn] + bias[jm]
//   q = clip(rint(x/s), +-127)   (small integer -> exact in bf16)
//   Wt[(j,m),(k,n)] = sum_p a0*sY*sZ*W[m,n] + a1*sY*Ysum[m] + a2*sZ*Zcol[n] + a3
//   W[m,n] = sum_l sgn(Y)sgn(Z) = 8 - 2*popc(Sy[m]^Sz[n]) (sign-bit masks)

typedef __attribute__((ext_vector_type(8))) short bf16x8;
typedef __attribute__((ext_vector_type(4))) float f32x4;
typedef __attribute__((ext_vector_type(4))) unsigned short us4;

__device__ __forceinline__ unsigned short f2bf(float f) {
    union { float f; uint32_t u; } c; c.f = f;
    uint32_t r = 0x7fffu + ((c.u >> 16) & 1u);
    return (unsigned short)((c.u + r) >> 16);
}

__device__ __forceinline__ void gl2lds16(const void* g, void* l) {
    __builtin_amdgcn_global_load_lds(
        (const __attribute__((address_space(1))) void*)g,
        (__attribute__((address_space(3))) void*)l, 16, 0, 0);
}

// ---------------------------------------------------------------------------
// Fused: blocks [0,1024) -> one (j,k) tile of Wt via ballot/popcount;
//        blocks [1024,1536) -> quantize x -> qx.
__global__ __launch_bounds__(256) void fused_pre(
    const float* __restrict__ Y,     // (2,32,32,32,8)
    const float* __restrict__ Z,     // (2,32,32,8,32)
    const float* __restrict__ A,     // (2,32,32,4)
    const float* __restrict__ x,     // (2048,1024)
    const float* __restrict__ act_scale,
    unsigned short* __restrict__ wt, // (1024 N, 1024 K) bf16 bits
    unsigned short* __restrict__ qx) // (2048,1024) bf16 bits
{
    const int t = threadIdx.x;

    if (blockIdx.x >= 1024) {
        const float s = fmaxf(fabsf(act_scale[0]), 1e-8f);
        const int b2 = blockIdx.x - 1024;
        #pragma unroll
        for (int it = 0; it < 4; ++it) {
            const size_t i4 = (size_t)b2 * 256 + t + (size_t)it * 131072;
            const float4 v = *(const float4*)(x + i4 * 4);
            us4 o;
            o.x = f2bf(fminf(fmaxf(rintf(v.x / s), -127.f), 127.f));
            o.y = f2bf(fminf(fmaxf(rintf(v.y / s), -127.f), 127.f));
            o.z = f2bf(fminf(fmaxf(rintf(v.z / s), -127.f), 127.f));
            o.w = f2bf(fminf(fmaxf(rintf(v.w / s), -127.f), 127.f));
            *(us4*)(qx + i4 * 4) = o;
        }
        return;
    }

    // sign-bit ballots: Y tile t=m*8+l (wave w -> m in [8w,8w+8)); byte b of
    // wave-w ballot = Sy[8w+b]. Z tile t=l*32+n (wave w -> l in {2w,2w+1});
    // word index l of zb = bits over n for that l.
    __shared__ unsigned int yb[2][8];   // [p][word]
    __shared__ unsigned int zb[2][8];   // [p][l]
    __shared__ float wred[16];

    const int jk = blockIdx.x;
    const int jj = jk >> 5;
    const int kk = jk & 31;
    const int n  = t & 31;
    const int mb = t >> 5;      // 0..7
    const int w  = t >> 6;
    const int lane = t & 63;

    const int base0 = jj * 32 + kk;
    const int base1 = 1024 + base0;

    const float yv0 = Y[(size_t)base0 * 256 + t];
    const float yv1 = Y[(size_t)base1 * 256 + t];
    const float zv0 = Z[(size_t)base0 * 256 + t];
    const float zv1 = Z[(size_t)base1 * 256 + t];
    const float a00 = A[(size_t)base0 * 4 + 0], a01 = A[(size_t)base0 * 4 + 1];
    const float a02 = A[(size_t)base0 * 4 + 2], a03 = A[(size_t)base0 * 4 + 3];
    const float a10 = A[(size_t)base1 * 4 + 0], a11 = A[(size_t)base1 * 4 + 1];
    const float a12 = A[(size_t)base1 * 4 + 2], a13 = A[(size_t)base1 * 4 + 3];

    const unsigned long long by0 = __ballot(yv0 < 0.f);
    const unsigned long long by1 = __ballot(yv1 < 0.f);
    const unsigned long long bz0 = __ballot(zv0 < 0.f);
    const unsigned long long bz1 = __ballot(zv1 < 0.f);
    if (lane == 0) {
        yb[0][2 * w] = (unsigned)by0; yb[0][2 * w + 1] = (unsigned)(by0 >> 32);
        yb[1][2 * w] = (unsigned)by1; yb[1][2 * w + 1] = (unsigned)(by1 >> 32);
        zb[0][2 * w] = (unsigned)bz0; zb[0][2 * w + 1] = (unsigned)(bz0 >> 32);
        zb[1][2 * w] = (unsigned)bz1; zb[1][2 * w + 1] = (unsigned)(bz1 >> 32);
    }

    float ay0 = fabsf(yv0), az0 = fabsf(zv0);
    float ay1 = fabsf(yv1), az1 = fabsf(zv1);
    #pragma unroll
    for (int d = 1; d < 64; d <<= 1) {
        ay0 += __shfl_xor(ay0, d, 64);
        az0 += __shfl_xor(az0, d, 64);
        ay1 += __shfl_xor(ay1, d, 64);
        az1 += __shfl_xor(az1, d, 64);
    }
    if (lane == 0) {
        wred[w * 4 + 0] = ay0;
        wred[w * 4 + 1] = az0;
        wred[w * 4 + 2] = ay1;
        wred[w * 4 + 3] = az1;
    }
    __syncthreads();

    const float sY0 = (wred[0] + wred[4] + wred[8]  + wred[12]) * (1.f / 256.f);
    const float sZ0 = (wred[1] + wred[5] + wred[9]  + wred[13]) * (1.f / 256.f);
    const float sY1 = (wred[2] + wred[6] + wred[10] + wred[14]) * (1.f / 256.f);
    const float sZ1 = (wred[3] + wred[7] + wred[11] + wred[15]) * (1.f / 256.f);

    const float c00 = a00 * sY0 * sZ0, c01 = a01 * sY0, c02 = a02 * sZ0;
    const float c10 = a10 * sY1 * sZ1, c11 = a11 * sY1, c12 = a12 * sZ1;
    const float cb  = a03 + a13;

    // assemble Sz[n] (8 bits over l) per p
    unsigned sz0 = 0, sz1 = 0;
    #pragma unroll
    for (int l = 0; l < 8; ++l) {
        sz0 |= ((zb[0][l] >> n) & 1u) << l;
        sz1 |= ((zb[1][l] >> n) & 1u) << l;
    }
    const float zc0 = 8.f - 2.f * (float)__popc(sz0);
    const float zc1 = 8.f - 2.f * (float)__popc(sz1);
    const float czc = c02 * zc0 + c12 * zc1 + cb;

    const int ybw = (mb >> 2);
    const int ybs = (mb & 3) * 8;

    #pragma unroll
    for (int q = 0; q < 4; ++q) {
        const int m = mb + 8 * q;
        const unsigned sy0 = (yb[0][2 * q + ybw] >> ybs) & 0xffu;
        const unsigned sy1 = (yb[1][2 * q + ybw] >> ybs) & 0xffu;
        const float w0  = 8.f - 2.f * (float)__popc(sy0 ^ sz0);
        const float w1  = 8.f - 2.f * (float)__popc(sy1 ^ sz1);
        const float ys0 = 8.f - 2.f * (float)__popc(sy0);
        const float ys1 = 8.f - 2.f * (float)__popc(sy1);
        const float acc = c00 * w0 + c01 * ys0 + c10 * w1 + c11 * ys1 + czc;
        wt[(size_t)(jj * 32 + m) * 1024 + kk * 32 + n] = f2bf(acc);
    }
}

// ---------------------------------------------------------------------------
// GEMM: out[2048,1024] = s * (Q[2048,K] x Wt[1024 N,K]^T) + bias
// 64(M) x 64(N) tile, grid (16,32)=512 blocks (2/CU), 4 waves 2x2,
// BK=64, double-buffered LDS, XOR-swizzled chunk layout:
//   LDS chunk(row, k8) stored at row*8 + (k8 ^ (row&7))  [chunk = 16B = 8 bf16]
// Swizzle applied on the GLOBAL address (global_load_lds dst is lane-linear).
__global__ __launch_bounds__(256) void gemm_mfma(
    const unsigned short* __restrict__ qx,   // (2048,1024) bf16 bits
    const unsigned short* __restrict__ wt,   // (1024,1024) bf16 bits
    const float* __restrict__ bias,          // (1024)
    const float* __restrict__ act_scale,     // (1)
    float* __restrict__ out)                 // (2048,1024)
{
    // buffer = A 64x64 (8KB) + B 64x64 (8KB); x2 buffers = 32KB
    __shared__ __align__(16) short lds[2 * 8192];

    const int tid  = threadIdx.x;
    const int lane = tid & 63;
    const int wave = tid >> 6;
    const int wm = wave >> 1;
    const int wn = wave & 1;
    const int rowBase = blockIdx.y * 64;
    const int colBase = blockIdx.x * 64;

    const float s = fmaxf(fabsf(act_scale[0]), 1e-8f);

    f32x4 acc[2][2];
    #pragma unroll
    for (int i = 0; i < 2; ++i)
        #pragma unroll
        for (int jx = 0; jx < 2; ++jx)
            acc[i][jx] = (f32x4)0.f;

    // staging: chunk c = (issue*4+wave)*64 + lane; row = c>>3, k8g = (c&7)^(row&7)
    const int lr = lane >> 3;                 // row&7 within group
    const int kx = (lane & 7) ^ lr;           // swizzled k-chunk
    const unsigned short* ag[2];
    const unsigned short* bg[2];
    #pragma unroll
    for (int i = 0; i < 2; ++i) {
        const int g = i * 4 + wave;           // 0..7
        ag[i] = qx + (size_t)(rowBase + g * 8 + lr) * 1024 + kx * 8;
        bg[i] = wt + (size_t)(colBase + g * 8 + lr) * 1024 + kx * 8;
    }

    char* const ldsc = (char*)lds;
    const int q4  = lane >> 4;
    const int l16 = lane & 15;

    // prologue: stage tile 0 into buffer 0
    #pragma unroll
    for (int i = 0; i < 2; ++i) {
        const int g = i * 4 + wave;
        gl2lds16(ag[i], ldsc + g * 1024);
        gl2lds16(bg[i], ldsc + 8192 + g * 1024);
    }

    for (int kt = 0; kt < 16; ++kt) {
        __syncthreads();   // buffer kt&1 ready (drains prefetch from prev iter)

        if (kt + 1 < 16) {
            const int k1 = (kt + 1) * 64;
            char* bb = ldsc + ((kt + 1) & 1) * 16384;
            #pragma unroll
            for (int i = 0; i < 2; ++i) {
                const int g = i * 4 + wave;
                gl2lds16(ag[i] + k1, bb + g * 1024);
                gl2lds16(bg[i] + k1, bb + 8192 + g * 1024);
            }
        }

        const short* As = lds + (kt & 1) * 8192;
        const short* Bs = As + 4096;

        #pragma unroll
        for (int kk2 = 0; kk2 < 2; ++kk2) {
            const int kc = kk2 * 4 + q4;
            bf16x8 af[2], bfr[2];
            #pragma unroll
            for (int im = 0; im < 2; ++im) {
                const int r = wm * 32 + im * 16 + l16;
                af[im] = *(const bf16x8*)&As[(r * 8 + (kc ^ (r & 7))) * 8];
            }
            #pragma unroll
            for (int in = 0; in < 2; ++in) {
                const int r = wn * 32 + in * 16 + l16;
                bfr[in] = *(const bf16x8*)&Bs[(r * 8 + (kc ^ (r & 7))) * 8];
            }
            #pragma unroll
            for (int im = 0; im < 2; ++im)
                #pragma unroll
                for (int in = 0; in < 2; ++in)
                    acc[im][in] = __builtin_amdgcn_mfma_f32_16x16x32_bf16(
                        af[im], bfr[in], acc[im][in], 0, 0, 0);
        }
    }

    // epilogue: C/D layout col = lane&15, row = quad*4 + reg
    #pragma unroll
    for (int im = 0; im < 2; ++im) {
        #pragma unroll
        for (int in = 0; in < 2; ++in) {
            const int col = colBase + wn * 32 + in * 16 + l16;
            const float b = bias[col];
            #pragma unroll
            for (int r = 0; r < 4; ++r) {
                const int row = rowBase + wm * 32 + im * 16 + q4 * 4 + r;
                out[(size_t)row * 1024 + col] = s * acc[im][in][r] + b;
            }
        }
    }
}

extern "C" void kernel_launch(void* const* d_in, const int* in_sizes, int n_in,
                              void* d_out, int out_size, void* d_ws, size_t ws_size,
                              hipStream_t stream) {
    const float* x         = (const float*)d_in[0];  // (2,1024,1024)
    const float* Y_fp      = (const float*)d_in[1];  // (2,32,32,32,8)
    const float* Z_fp      = (const float*)d_in[2];  // (2,32,32,8,32)
    const float* A         = (const float*)d_in[3];  // (2,32,32,4)
    const float* bias      = (const float*)d_in[4];  // (1024)
    const float* act_scale = (const float*)d_in[5];  // (1)
    float* out = (float*)d_out;                      // (2048,1024)

    unsigned short* wtp = (unsigned short*)d_ws;                            // 2 MB
    unsigned short* qxp = (unsigned short*)((char*)d_ws + 2 * 1024 * 1024); // 4 MB

    fused_pre<<<dim3(1536), dim3(256), 0, stream>>>(Y_fp, Z_fp, A, x, act_scale, wtp, qxp);
    gemm_mfma<<<dim3(16, 32), dim3(256), 0, stream>>>(qxp, wtp, bias, act_scale, out);
}